// Round 13
// baseline (27.164 us; speedup 1.0000x reference)
//
#include <hip/hip_runtime.h>
#include <hip/hip_bf16.h>
#include <hip/hip_fp16.h>

// Problem constants (match reference)
#define MB 4096      // B rows
#define MD 4096      // D classes
#define MP 8         // P positives per row
#define MARGIN 0.5f

typedef float    f32x4 __attribute__((ext_vector_type(4)));
typedef _Float16 f16x4 __attribute__((ext_vector_type(4)));
typedef _Float16 f16x2 __attribute__((ext_vector_type(2)));

// ===== R13 MEASUREMENT ROUND =====
// R11 kernel verbatim (best: 16.83us, nt loads proven +2.1us vs plain in
// R12). Stage-1 is launched TWICE: idempotent (writes identical ws), so
// correctness/determinism unchanged. dur_us - 16.83 = stage-1's steady-state
// marginal cost incl. graph-node gap — the stage-1/stage-2 split has been
// guessed wrong twice (R10, R12); this measures it.
__global__ __launch_bounds__(256) void margin_rows_kernel(
    const float* __restrict__ x,
    const int* __restrict__ pos_ids,
    float* __restrict__ ws)
{
    const int row = blockIdx.x;
    const int t = threadIdx.x;
    const int lane = t & 63;
    const int wave = t >> 6;
    const float* __restrict__ xr = x + (size_t)row * MD;

    // Longest dependency chain first: pos_ids -> gather -> shfl broadcast.
    const int p = pos_ids[row * MP + (lane & 7)];

    // Independent streaming loads — issue early, overlap with the gather.
    const f32x4* __restrict__ xr4 = reinterpret_cast<const f32x4*>(xr);
    const f32x4 v0 = __builtin_nontemporal_load(xr4 + t);
    const f32x4 v1 = __builtin_nontemporal_load(xr4 + 256 + t);
    const f32x4 v2 = __builtin_nontemporal_load(xr4 + 512 + t);
    const f32x4 v3 = __builtin_nontemporal_load(xr4 + 768 + t);

    const float xg = xr[p];   // 8 unique addrs/wave (cache hits)

    // Thresholds: f16-round once; keep the exact f32 image for cancellation.
    f16x2 th2[MP];
    float th[MP];
    int   pi[MP];
    float sum_th = 0.0f;
#pragma unroll
    for (int k = 0; k < MP; ++k) {
        const float thf = __shfl(xg, k, 64) - MARGIN;
        const _Float16 thh = (_Float16)thf;
        th2[k] = (f16x2){thh, thh};
        th[k] = (float)thh;
        pi[k] = __shfl(p, k, 64);
        sum_th += th[k];
    }

    // Convert the 16 columns to f16 (natural pair packing).
    const f16x4 h0 = __builtin_convertvector(v0, f16x4);
    const f16x4 h1 = __builtin_convertvector(v1, f16x4);
    const f16x4 h2 = __builtin_convertvector(v2, f16x4);
    const f16x4 h3 = __builtin_convertvector(v3, f16x4);
    const f16x2 pr[8] = { h0.xy, h0.zw, h1.xy, h1.zw,
                          h2.xy, h2.zw, h3.xy, h3.zw };

    // Packed hinge sums: acc[k&3] += pk_max(pair, th2[k]).
    f16x2 pa0 = (f16x2)0, pa1 = (f16x2)0, pa2 = (f16x2)0, pa3 = (f16x2)0;
#pragma unroll
    for (int j = 0; j < 8; ++j) {
        const f16x2 vp = pr[j];
        pa0 += __builtin_elementwise_max(vp, th2[0]);
        pa1 += __builtin_elementwise_max(vp, th2[1]);
        pa2 += __builtin_elementwise_max(vp, th2[2]);
        pa3 += __builtin_elementwise_max(vp, th2[3]);
        pa0 += __builtin_elementwise_max(vp, th2[4]);
        pa1 += __builtin_elementwise_max(vp, th2[5]);
        pa2 += __builtin_elementwise_max(vp, th2[6]);
        pa3 += __builtin_elementwise_max(vp, th2[7]);
    }
    const f16x2 ps = (pa0 + pa1) + (pa2 + pa3);
    float acc0 = (float)ps.x + (float)ps.y;
    float acc1 = 0.0f;

    // Remove the -th_k terms in one shot: 16 columns x sum_th (exact f32
    // image of the f16 thresholds => cancels the hot loop's th selections).
    acc0 -= 16.0f * sum_th;

    // Positive-column correction: lane l (<8) subtracts the contribution of
    // anchor column pos[l] (dedup duplicates: y[i,d]=1 regardless of repeats).
    if (t < MP) {
        bool dup = false;
#pragma unroll
        for (int k2 = 0; k2 < MP; ++k2) dup = dup || (k2 < t && pi[k2] == pi[t]);
        if (!dup) {
            const float xk = th[t] + MARGIN;   // = x[row, pos_t] (f16 image)
#pragma unroll
            for (int j = 0; j < MP; ++j)
                acc1 -= fmaxf(0.0f, xk - th[j]);
        }
    }

    float acc = acc0 + acc1;
#pragma unroll
    for (int off = 32; off > 0; off >>= 1)
        acc += __shfl_down(acc, off, 64);

    __shared__ float s_part[4];
    if (lane == 0) s_part[wave] = acc;
    __syncthreads();
    if (t == 0)
        ws[row] = s_part[0] + s_part[1] + s_part[2] + s_part[3];
}

// Stage 2: one block reduces MB partials (double accumulation, fixed order).
__global__ __launch_bounds__(256) void margin_final_kernel(
    const float* __restrict__ ws,
    float* __restrict__ out)
{
    const int t = threadIdx.x;
    double acc = 0.0;
#pragma unroll
    for (int it = 0; it < MB / 256; ++it)
        acc += (double)ws[it * 256 + t];

#pragma unroll
    for (int off = 32; off > 0; off >>= 1)
        acc += __shfl_down(acc, off, 64);

    __shared__ double s_part[4];
    const int wave = t >> 6;
    if ((t & 63) == 0) s_part[wave] = acc;
    __syncthreads();
    if (t == 0) {
        const double tot = s_part[0] + s_part[1] + s_part[2] + s_part[3];
        const double count = (double)MB * (double)MP * (double)(MD - MP);
        out[0] = (float)(tot / count);
    }
}

extern "C" void kernel_launch(void* const* d_in, const int* in_sizes, int n_in,
                              void* d_out, int out_size, void* d_ws, size_t ws_size,
                              hipStream_t stream) {
    const float* x = (const float*)d_in[0];
    // d_in[1] is y, redundant with pos_ids — not read (halves HBM traffic).
    const int* pos_ids = (const int*)d_in[2];
    float* out = (float*)d_out;
    float* ws = (float*)d_ws;  // MB floats = 16 KB of scratch

    // PROBE: stage-1 twice (idempotent). dur_us - 16.83 = s1 marginal cost.
    margin_rows_kernel<<<MB, 256, 0, stream>>>(x, pos_ids, ws);
    margin_rows_kernel<<<MB, 256, 0, stream>>>(x, pos_ids, ws);
    margin_final_kernel<<<1, 256, 0, stream>>>(ws, out);
}

// Round 14
// 16.825 us; speedup vs baseline: 1.6145x; 1.6145x over previous
//
#include <hip/hip_runtime.h>
#include <hip/hip_bf16.h>
#include <hip/hip_fp16.h>

// Problem constants (match reference)
#define MB 4096      // B rows
#define MD 4096      // D classes
#define MP 8         // P positives per row
#define MARGIN 0.5f

typedef float    f32x4 __attribute__((ext_vector_type(4)));
typedef _Float16 f16x4 __attribute__((ext_vector_type(4)));
typedef _Float16 f16x2 __attribute__((ext_vector_type(2)));

// Stage 1 (R11 verbatim — measured AT the HBM roofline: R13 dual-launch
// probe gave 10.33us marginal vs 9.8us floor for 64MiB @ 6.85TB/s).
// One block per row, grid 4096; packed-f16 hinge identity hot loop; nt
// loads (R12: plain loads +2.1us); positive-column correction in lanes 0-7.
// Fused one-kernel finishes rejected thrice (R5/R6/R8: agent-scope atomic
// waiting costs more than a kernel boundary on non-coherent XCD L2s).
__global__ __launch_bounds__(256) void margin_rows_kernel(
    const float* __restrict__ x,
    const int* __restrict__ pos_ids,
    float* __restrict__ ws)
{
    const int row = blockIdx.x;
    const int t = threadIdx.x;
    const int lane = t & 63;
    const int wave = t >> 6;
    const float* __restrict__ xr = x + (size_t)row * MD;

    // Longest dependency chain first: pos_ids -> gather -> shfl broadcast.
    const int p = pos_ids[row * MP + (lane & 7)];

    // Independent streaming loads — issue early, overlap with the gather.
    const f32x4* __restrict__ xr4 = reinterpret_cast<const f32x4*>(xr);
    const f32x4 v0 = __builtin_nontemporal_load(xr4 + t);
    const f32x4 v1 = __builtin_nontemporal_load(xr4 + 256 + t);
    const f32x4 v2 = __builtin_nontemporal_load(xr4 + 512 + t);
    const f32x4 v3 = __builtin_nontemporal_load(xr4 + 768 + t);

    const float xg = xr[p];   // 8 unique addrs/wave (cache hits)

    // Thresholds: f16-round once; keep the exact f32 image for cancellation.
    f16x2 th2[MP];
    float th[MP];
    int   pi[MP];
    float sum_th = 0.0f;
#pragma unroll
    for (int k = 0; k < MP; ++k) {
        const float thf = __shfl(xg, k, 64) - MARGIN;
        const _Float16 thh = (_Float16)thf;
        th2[k] = (f16x2){thh, thh};
        th[k] = (float)thh;
        pi[k] = __shfl(p, k, 64);
        sum_th += th[k];
    }

    // Convert the 16 columns to f16 (natural pair packing).
    const f16x4 h0 = __builtin_convertvector(v0, f16x4);
    const f16x4 h1 = __builtin_convertvector(v1, f16x4);
    const f16x4 h2 = __builtin_convertvector(v2, f16x4);
    const f16x4 h3 = __builtin_convertvector(v3, f16x4);
    const f16x2 pr[8] = { h0.xy, h0.zw, h1.xy, h1.zw,
                          h2.xy, h2.zw, h3.xy, h3.zw };

    // Packed hinge sums: acc[k&3] += pk_max(pair, th2[k]).
    f16x2 pa0 = (f16x2)0, pa1 = (f16x2)0, pa2 = (f16x2)0, pa3 = (f16x2)0;
#pragma unroll
    for (int j = 0; j < 8; ++j) {
        const f16x2 vp = pr[j];
        pa0 += __builtin_elementwise_max(vp, th2[0]);
        pa1 += __builtin_elementwise_max(vp, th2[1]);
        pa2 += __builtin_elementwise_max(vp, th2[2]);
        pa3 += __builtin_elementwise_max(vp, th2[3]);
        pa0 += __builtin_elementwise_max(vp, th2[4]);
        pa1 += __builtin_elementwise_max(vp, th2[5]);
        pa2 += __builtin_elementwise_max(vp, th2[6]);
        pa3 += __builtin_elementwise_max(vp, th2[7]);
    }
    const f16x2 ps = (pa0 + pa1) + (pa2 + pa3);
    float acc0 = (float)ps.x + (float)ps.y;
    float acc1 = 0.0f;

    // Remove the -th_k terms in one shot: 16 columns x sum_th (exact f32
    // image of the f16 thresholds => cancels the hot loop's th selections).
    acc0 -= 16.0f * sum_th;

    // Positive-column correction: lane l (<8) subtracts the contribution of
    // anchor column pos[l] (dedup duplicates: y[i,d]=1 regardless of repeats).
    if (t < MP) {
        bool dup = false;
#pragma unroll
        for (int k2 = 0; k2 < MP; ++k2) dup = dup || (k2 < t && pi[k2] == pi[t]);
        if (!dup) {
            const float xk = th[t] + MARGIN;   // = x[row, pos_t] (f16 image)
#pragma unroll
            for (int j = 0; j < MP; ++j)
                acc1 -= fmaxf(0.0f, xk - th[j]);
        }
    }

    float acc = acc0 + acc1;
#pragma unroll
    for (int off = 32; off > 0; off >>= 1)
        acc += __shfl_down(acc, off, 64);

    __shared__ float s_part[4];
    if (lane == 0) s_part[wave] = acc;
    __syncthreads();
    if (t == 0)
        ws[row] = s_part[0] + s_part[1] + s_part[2] + s_part[3];
}

// Stage 2 (R14: widened): 1024 threads, one f32x4 load per thread covers all
// 4096 partials in a single fully-parallel load round-trip (was 16 scalar
// loads x 256 threads). Fixed-order double reduction => deterministic.
__global__ __launch_bounds__(1024) void margin_final_kernel(
    const float* __restrict__ ws,
    float* __restrict__ out)
{
    const int t = threadIdx.x;
    const int lane = t & 63;
    const int wave = t >> 6;   // 16 waves

    const f32x4 v = reinterpret_cast<const f32x4*>(ws)[t];
    double acc = ((double)v.x + (double)v.y) + ((double)v.z + (double)v.w);

#pragma unroll
    for (int off = 32; off > 0; off >>= 1)
        acc += __shfl_down(acc, off, 64);

    __shared__ double s_part[16];
    if (lane == 0) s_part[wave] = acc;
    __syncthreads();

    if (t < 16) {
        double d = s_part[t];
#pragma unroll
        for (int off = 8; off > 0; off >>= 1)
            d += __shfl_down(d, off, 64);
        if (t == 0) {
            const double count = (double)MB * (double)MP * (double)(MD - MP);
            out[0] = (float)(d / count);
        }
    }
}

extern "C" void kernel_launch(void* const* d_in, const int* in_sizes, int n_in,
                              void* d_out, int out_size, void* d_ws, size_t ws_size,
                              hipStream_t stream) {
    const float* x = (const float*)d_in[0];
    // d_in[1] is y, redundant with pos_ids — not read (halves HBM traffic).
    const int* pos_ids = (const int*)d_in[2];
    float* out = (float*)d_out;
    float* ws = (float*)d_ws;  // MB floats = 16 KB of scratch

    margin_rows_kernel<<<MB, 256, 0, stream>>>(x, pos_ids, ws);
    margin_final_kernel<<<1, 1024, 0, stream>>>(ws, out);
}